// Round 1
// baseline (233.424 us; speedup 1.0000x reference)
//
#include <hip/hip_runtime.h>

// B=16, L=2048, K=24, D=64
typedef _Float16 f16;
typedef _Float16 f16x4 __attribute__((ext_vector_type(4)));
typedef _Float16 f16x8 __attribute__((ext_vector_type(8)));
typedef float f32x4 __attribute__((ext_vector_type(4)));

__device__ __forceinline__ void gl_lds16(const void* g, void* l) {
  __builtin_amdgcn_global_load_lds(
      (__attribute__((address_space(1))) unsigned int*)(g),
      (__attribute__((address_space(3))) unsigned int*)(l), 16, 0, 0);
}

// ---- k_pre0: ALL independent precompute arms in launch #1 (728 blocks) —
// they ride the otherwise-idle machine during what used to be a 24-block
// k_phi dispatch. Arms:
//   blk 0..255:   uin conversion — in[b][s0+row][cg*8..+8] (fp32) -> f16,
//                 PRE-SWIZZLED planes of 8192 so k_w can stage U with
//                 contiguous gl_lds16 (same trick as phiT staging).
//   blk 256..279: phiT[k][e][d] = (f16) m_phi[(k*64+d)*64+e]
//   blk 280..663: Dpre phase-replicated Toeplitz tables (R15)
//   blk 664..727: zero out[]
__global__ __launch_bounds__(256) void k_pre0(const float* __restrict__ in,
                                              const float* __restrict__ m_phi,
                                              const float* __restrict__ ev,
                                              const float* __restrict__ evec,
                                              f16* __restrict__ phiT,
                                              f16* __restrict__ uin,
                                              f16* __restrict__ Dpre,
                                              float* __restrict__ out) {
  __shared__ float esm[256];
  int blk = blockIdx.x;
  int tid = threadIdx.x;
  if (blk < 256) {  // ---- uin conversion (one 128-s x 64-d plane per block)
    int b = blk >> 4, s0 = (blk & 15) * 128;
    f16* up = uin + (size_t)blk * 8192;
#pragma unroll
    for (int v = 0; v < 4; ++v) {
      int flat = v * 256 + tid;
      int row = flat >> 3, cl = flat & 7, cg = cl ^ (row & 7);
      const float* g = in + ((size_t)(b * 2048 + s0 + row)) * 64 + cg * 8;
      float4 u0 = *(const float4*)g;
      float4 u1 = *(const float4*)(g + 4);
      f16x8 h;
      h[0] = (f16)u0.x; h[1] = (f16)u0.y; h[2] = (f16)u0.z; h[3] = (f16)u0.w;
      h[4] = (f16)u1.x; h[5] = (f16)u1.y; h[6] = (f16)u1.z; h[7] = (f16)u1.w;
      *(f16x8*)&up[flat * 8] = h;
    }
    return;
  }
  if (blk < 280) {  // ---- phiT transpose
    int k = blk - 256;
    for (int idx = tid; idx < 4096; idx += 256) {
      int e = idx >> 6, d = idx & 63;
      phiT[k * 4096 + idx] = (f16)m_phi[(k * 64 + d) * 64 + e];
    }
    return;
  }
  if (blk < 664) {  // ---- Dpre blocks (384): D[p][y]=esm[254-p-y], pad 2560
    int a = blk - 280;
    int diag = a / 24, k = a % 24;
    float s4 = sqrtf(sqrtf(ev[k]));
    int base = diag * 128 - 127;
    if (tid < 255) {
      int v = base + tid;
      esm[tid] = (v >= 0) ? evec[v * 24 + k] * s4 : 0.0f;
    }
    __syncthreads();
    f16* plane = Dpre + (size_t)(diag * 24 + k) * 2560;
    for (int i = tid; i < 2560; i += 256) {
      float val = 0.f;
      if (i < 2112) {
        int p = i / 264, y = i - p * 264;
        int g = 254 - p - y;
        if (g >= 0) val = esm[g];
      }
      plane[i] = (f16)val;
    }
    return;
  }
  // ---- zero-out blocks: 64 blocks x 32768 floats
  float4* o = (float4*)(out + (size_t)(blk - 664) * 32768);
  float4 z4 = {0.f, 0.f, 0.f, 0.f};
#pragma unroll
  for (int i = 0; i < 32; ++i) o[i * 256 + tid] = z4;
}

// ---- k_w: W2T[b][k][e][s] = sum_d in[b][s][d] * m_phi[k*64+d][e]  (f16 out)
// PURE k_w launch (1536 blocks, arms moved to k_pre0). U staged via 4
// contiguous gl_lds16 from pre-swizzled uin (no fp32 loads / converts /
// ds_writes in the prologue); P(k0) prefetched into the same vmcnt group.
__global__ __launch_bounds__(256) void k_w(const f16* __restrict__ uin,
                                           const f16* __restrict__ phiT,
                                           f16* __restrict__ W2T) {
  __shared__ __align__(16) f16 Ubuf[8320];
  __shared__ __align__(16) f16 Psm[64 * 64];
  int wblk = blockIdx.x;
  int s0 = (wblk & 15) * 128;
  int b = (wblk >> 4) & 15;
  int kg = wblk >> 8;  // 0..5
  int tid = threadIdx.x, lane = tid & 63, wv = tid >> 6;
  const f16* up = uin + (size_t)(wblk & 255) * 8192;
  // U stage: contiguous gl_lds (uin pre-swizzled by k_pre0)
#pragma unroll
  for (int v = 0; v < 4; ++v)
    gl_lds16(up + (size_t)(v * 256 + tid) * 8, &Ubuf[(v * 256 + wv * 64) * 8]);
  // P(k0) stage in the same vmcnt group
  {
    int k0 = kg * 4;
#pragma unroll
    for (int v = 0; v < 2; ++v) {
      int flat = v * 256 + tid;
      int row = flat >> 3, cl = flat & 7, cg = cl ^ (row & 7);
      gl_lds16(phiT + (size_t)k0 * 4096 + row * 64 + cg * 8,
               &Psm[(v * 256 + wv * 64) * 8]);
    }
  }
  __syncthreads();  // U + P0 resident
  int wm = wv * 32;
  f16x8 af[2][2];
#pragma unroll
  for (int ks = 0; ks < 2; ++ks)
#pragma unroll
    for (int x = 0; x < 2; ++x) {
      int m = wm + x * 16 + (lane & 15);
      int ch = (ks * 4 + (lane >> 4)) ^ (m & 7);
      af[ks][x] = *(const f16x8*)&Ubuf[m * 64 + ch * 8];
    }
  for (int ki = 0; ki < 4; ++ki) {
    int k = kg * 4 + ki;
    f32x4 zero = {0.f, 0.f, 0.f, 0.f};
    f32x4 acc[2][4];
#pragma unroll
    for (int x = 0; x < 2; ++x)
#pragma unroll
      for (int y = 0; y < 4; ++y) acc[x][y] = zero;
#pragma unroll
    for (int ks = 0; ks < 2; ++ks) {
      f16x8 bf[4];
#pragma unroll
      for (int y = 0; y < 4; ++y) {
        int n = y * 16 + (lane & 15);
        int ch = (ks * 4 + (lane >> 4)) ^ (n & 7);
        bf[y] = *(const f16x8*)&Psm[n * 64 + ch * 8];
      }
#pragma unroll
      for (int x = 0; x < 2; ++x)
#pragma unroll
        for (int y = 0; y < 4; ++y)
          acc[x][y] = __builtin_amdgcn_mfma_f32_16x16x32_f16(af[ks][x], bf[y], acc[x][y], 0, 0, 0);
    }
    __syncthreads();  // Psm reads + (iter0) af Ubuf reads done everywhere
    // transpose C (128 sigma x 64 e) into Ubuf as Csm[e][sigma], stride 130
#pragma unroll
    for (int x = 0; x < 2; ++x)
#pragma unroll
      for (int y = 0; y < 4; ++y) {
        int e = y * 16 + (lane & 15);
        int sg = wm + x * 16 + ((lane >> 4) << 2);
        f16x4 pk;
        pk[0] = (f16)acc[x][y][0]; pk[1] = (f16)acc[x][y][1];
        pk[2] = (f16)acc[x][y][2]; pk[3] = (f16)acc[x][y][3];
        *(f16x4*)&Ubuf[e * 130 + sg] = pk;
      }
    if (ki < 3) {  // prefetch next P (Psm safe to overwrite after sync above)
      int kn = k + 1;
#pragma unroll
      for (int v = 0; v < 2; ++v) {
        int flat = v * 256 + tid;
        int row = flat >> 3, cl = flat & 7, cg = cl ^ (row & 7);
        gl_lds16(phiT + (size_t)kn * 4096 + row * 64 + cg * 8,
                 &Psm[(v * 256 + wv * 64) * 8]);
      }
    }
    __syncthreads();  // Csm visible; P(kn) drained (implicit vmcnt(0))
    // coalesced stores: 1024 chunks of 16B; 16 lanes cover 256B of one e-row
#pragma unroll
    for (int pass = 0; pass < 4; ++pass) {
      int g = pass * 256 + tid;
      int e = g >> 4, ch = g & 15;
      f16x8 val = *(const f16x8*)&Ubuf[e * 130 + ch * 8];
      *(f16x8*)&W2T[((size_t)((b * 24 + k) * 64 + e)) * 2048 + s0 + ch * 8] = val;
    }
  }
}

// ---- k_main: causal block-Toeplitz GEMM, 128x128 tiles, diag-major grid.
// R16: 2-deep software pipeline (T3-minimal + T4 counted vmcnt + T5 setprio).
// Double-buffered Bsm/Dsm (74 KB LDS -> 2 blocks/CU, same as measured
// effective occupancy). stage(k+1) issued BEFORE compute(k); raw s_barrier
// (no implicit vmcnt(0) drain) + per-wave counted s_waitcnt vmcnt(N) keeps
// the next tile's gl_lds in flight under the MFMA cluster. Compute body,
// swizzles, and epilogue identical to R15.
__global__ __launch_bounds__(256, 2) void k_main(const f16* __restrict__ Dpre,
                                                 const f16* __restrict__ W2T,
                                                 float* __restrict__ out) {
  __shared__ __align__(16) f16 Bsm[2][128 * 128];  // 64 KB
  __shared__ __align__(16) f16 Dsm[2][2560];       // 10 KB
  int nt = blockIdx.x;
  int q = blockIdx.y;
  int diag = 0, off = 0;
  while (off + (16 - diag) <= q) { off += 16 - diag; ++diag; }
  int st = q - off;
  int mt = st + diag;
  int tid = threadIdx.x, lane = tid & 63, wv = tid >> 6;
  int wm = (wv & 1) * 64, wn = (wv >> 1) * 64;
  int b0 = nt * 2;
  int ml = lane & 15, qv = lane >> 4;
  int p264 = (7 - (ml & 7)) * 264;           // phase row in Dsm
  int yb = (ml < 8 ? 120 : 112) - wm;        // y0 = s0 - x*16 + yb

  f32x4 zero = {0.f, 0.f, 0.f, 0.f};
  f32x4 acc[4][4];
#pragma unroll
  for (int x = 0; x < 4; ++x)
#pragma unroll
    for (int y = 0; y < 4; ++y) acc[x][y] = zero;

  const f16* dplane = Dpre + (size_t)(diag * 24) * 2560;

  // stage tile k into buffer buf: per-wave vmem ops = 9 (wave 0: 10).
  auto stage = [&](int buf, int kk) {
    const f16* dk = dplane + kk * 2560;
    // D table: 320 chunks (256 all-waves + 64 by wave 0; source padded)
    gl_lds16(dk + tid * 8, &Dsm[buf][wv * 512]);
    if (wv == 0) gl_lds16(dk + (256 + lane) * 8, &Dsm[buf][2048]);
    // B tile: 128 n-rows x 128 s (32 KB), XOR-swizzled 16B chunks
#pragma unroll
    for (int v = 0; v < 8; ++v) {
      int flat = v * 256 + tid;
      int row = flat >> 4, cl = flat & 15, cg = cl ^ (row & 15);
      int bb = b0 + (row >> 6), e = row & 63;
      gl_lds16(W2T + ((size_t)((bb * 24 + kk) * 64 + e)) * 2048 + st * 128 + cg * 8,
               &Bsm[buf][(v * 256 + wv * 64) * 8]);
    }
  };

  stage(0, 0);  // prologue: k=0 in flight

#pragma unroll 2
  for (int k = 0; k < 24; ++k) {
    const int cur = k & 1;
    if (k < 23) {
      stage(cur ^ 1, k + 1);  // issue next tile; stays in flight across compute
      __builtin_amdgcn_sched_barrier(0);
      // wait for stage(k) only: newest (k+1) stage keeps 9/10 ops outstanding
      if (wv == 0)
        asm volatile("s_waitcnt vmcnt(10)" ::: "memory");
      else
        asm volatile("s_waitcnt vmcnt(9)" ::: "memory");
    } else {
      asm volatile("s_waitcnt vmcnt(0)" ::: "memory");
    }
    __builtin_amdgcn_s_barrier();  // stage(k) visible to all waves
    __builtin_amdgcn_sched_barrier(0);
    __builtin_amdgcn_s_setprio(1);
#pragma unroll
    for (int ks = 0; ks < 4; ++ks) {
      int s0q = ks * 32 + qv * 8;
      f16x8 af[4], bf[4];
#pragma unroll
      for (int x = 0; x < 4; ++x)
        af[x] = *(const f16x8*)&Dsm[cur][p264 + s0q - x * 16 + yb];
#pragma unroll
      for (int y = 0; y < 4; ++y) {
        int n = wn + y * 16 + ml;
        int cl = (ks * 4 + qv) ^ (n & 15);
        bf[y] = *(const f16x8*)&Bsm[cur][n * 128 + cl * 8];
      }
#pragma unroll
      for (int x = 0; x < 4; ++x)
#pragma unroll
        for (int y = 0; y < 4; ++y)
          acc[x][y] = __builtin_amdgcn_mfma_f32_16x16x32_f16(af[x], bf[y], acc[x][y], 0, 0, 0);
    }
    __builtin_amdgcn_s_setprio(0);
    __builtin_amdgcn_sched_barrier(0);
    asm volatile("" ::: "memory");
    __builtin_amdgcn_s_barrier();  // buf[cur] reads done; k+1 may overwrite it
    asm volatile("" ::: "memory");
  }

  int t0 = mt * 128 + wm;
  int n0 = nt * 128 + wn;
#pragma unroll
  for (int x = 0; x < 4; ++x) {
    int rbase = t0 + x * 16 + (qv << 2);
#pragma unroll
    for (int y = 0; y < 4; ++y) {
      int col = n0 + y * 16 + ml;
      int b = col >> 6, e = col & 63;
#pragma unroll
      for (int r = 0; r < 4; ++r)
        atomicAdd(&out[((size_t)(b * 2048 + rbase + r)) * 64 + e], acc[x][y][r]);
    }
  }
}

extern "C" void kernel_launch(void* const* d_in, const int* in_sizes, int n_in,
                              void* d_out, int out_size, void* d_ws, size_t ws_size,
                              hipStream_t stream) {
  const float* inputs = (const float*)d_in[0];  // [16,2048,64]
  const float* m_phi = (const float*)d_in[1];   // [1536,64]
  const float* ev = (const float*)d_in[2];      // [24]
  const float* evec = (const float*)d_in[3];    // [2048,24]
  float* out = (float*)d_out;                   // [16,2048,64] fp32
  char* ws = (char*)d_ws;
  // ws layout: Dpre 1,966,080 | phiT 196,608 | uin 4,194,304 | W2T 100,663,296
  f16* Dpre = (f16*)(ws);
  f16* phiT = (f16*)(ws + 1966080);
  f16* uin = (f16*)(ws + 2162688);
  f16* W2T = (f16*)(ws + 6356992);

  hipLaunchKernelGGL(k_pre0, dim3(728), dim3(256), 0, stream,
                     inputs, m_phi, ev, evec, phiT, uin, Dpre, out);
  hipLaunchKernelGGL(k_w, dim3(1536), dim3(256), 0, stream, uin, phiT, W2T);
  hipLaunchKernelGGL(k_main, dim3(8, 136), dim3(256), 0, stream, Dpre, W2T, out);
}

// Round 2
// 223.391 us; speedup vs baseline: 1.0449x; 1.0449x over previous
//
#include <hip/hip_runtime.h>

// B=16, L=2048, K=24, D=64
typedef _Float16 f16;
typedef _Float16 f16x4 __attribute__((ext_vector_type(4)));
typedef _Float16 f16x8 __attribute__((ext_vector_type(8)));
typedef float f32x4 __attribute__((ext_vector_type(4)));

__device__ __forceinline__ void gl_lds16(const void* g, void* l) {
  __builtin_amdgcn_global_load_lds(
      (__attribute__((address_space(1))) unsigned int*)(g),
      (__attribute__((address_space(3))) unsigned int*)(l), 16, 0, 0);
}

// ---- k_pre0: ALL independent precompute arms in launch #1 (728 blocks).
//   blk 0..255:   uin conversion (pre-swizzled f16 planes for k_w)
//   blk 256..279: phiT[k][e][d] = (f16) m_phi[(k*64+d)*64+e]
//   blk 280..663: Dpre phase-replicated Toeplitz tables
//   blk 664..727: zero out[]
__global__ __launch_bounds__(256) void k_pre0(const float* __restrict__ in,
                                              const float* __restrict__ m_phi,
                                              const float* __restrict__ ev,
                                              const float* __restrict__ evec,
                                              f16* __restrict__ phiT,
                                              f16* __restrict__ uin,
                                              f16* __restrict__ Dpre,
                                              float* __restrict__ out) {
  __shared__ float esm[256];
  int blk = blockIdx.x;
  int tid = threadIdx.x;
  if (blk < 256) {  // ---- uin conversion (one 128-s x 64-d plane per block)
    int b = blk >> 4, s0 = (blk & 15) * 128;
    f16* up = uin + (size_t)blk * 8192;
#pragma unroll
    for (int v = 0; v < 4; ++v) {
      int flat = v * 256 + tid;
      int row = flat >> 3, cl = flat & 7, cg = cl ^ (row & 7);
      const float* g = in + ((size_t)(b * 2048 + s0 + row)) * 64 + cg * 8;
      float4 u0 = *(const float4*)g;
      float4 u1 = *(const float4*)(g + 4);
      f16x8 h;
      h[0] = (f16)u0.x; h[1] = (f16)u0.y; h[2] = (f16)u0.z; h[3] = (f16)u0.w;
      h[4] = (f16)u1.x; h[5] = (f16)u1.y; h[6] = (f16)u1.z; h[7] = (f16)u1.w;
      *(f16x8*)&up[flat * 8] = h;
    }
    return;
  }
  if (blk < 280) {  // ---- phiT transpose
    int k = blk - 256;
    for (int idx = tid; idx < 4096; idx += 256) {
      int e = idx >> 6, d = idx & 63;
      phiT[k * 4096 + idx] = (f16)m_phi[(k * 64 + d) * 64 + e];
    }
    return;
  }
  if (blk < 664) {  // ---- Dpre blocks (384): D[p][y]=esm[254-p-y], pad 2560
    int a = blk - 280;
    int diag = a / 24, k = a % 24;
    float s4 = sqrtf(sqrtf(ev[k]));
    int base = diag * 128 - 127;
    if (tid < 255) {
      int v = base + tid;
      esm[tid] = (v >= 0) ? evec[v * 24 + k] * s4 : 0.0f;
    }
    __syncthreads();
    f16* plane = Dpre + (size_t)(diag * 24 + k) * 2560;
    for (int i = tid; i < 2560; i += 256) {
      float val = 0.f;
      if (i < 2112) {
        int p = i / 264, y = i - p * 264;
        int g = 254 - p - y;
        if (g >= 0) val = esm[g];
      }
      plane[i] = (f16)val;
    }
    return;
  }
  // ---- zero-out blocks: 64 blocks x 32768 floats
  float4* o = (float4*)(out + (size_t)(blk - 664) * 32768);
  float4 z4 = {0.f, 0.f, 0.f, 0.f};
#pragma unroll
  for (int i = 0; i < 32; ++i) o[i * 256 + tid] = z4;
}

// ---- k_w: W2T[b][k][e][s] = sum_d in[b][s][d] * m_phi[k*64+d][e]  (f16 out)
__global__ __launch_bounds__(256) void k_w(const f16* __restrict__ uin,
                                           const f16* __restrict__ phiT,
                                           f16* __restrict__ W2T) {
  __shared__ __align__(16) f16 Ubuf[8320];
  __shared__ __align__(16) f16 Psm[64 * 64];
  int wblk = blockIdx.x;
  int s0 = (wblk & 15) * 128;
  int b = (wblk >> 4) & 15;
  int kg = wblk >> 8;  // 0..5
  int tid = threadIdx.x, lane = tid & 63, wv = tid >> 6;
  const f16* up = uin + (size_t)(wblk & 255) * 8192;
  // U stage: contiguous gl_lds (uin pre-swizzled by k_pre0)
#pragma unroll
  for (int v = 0; v < 4; ++v)
    gl_lds16(up + (size_t)(v * 256 + tid) * 8, &Ubuf[(v * 256 + wv * 64) * 8]);
  // P(k0) stage in the same vmcnt group
  {
    int k0 = kg * 4;
#pragma unroll
    for (int v = 0; v < 2; ++v) {
      int flat = v * 256 + tid;
      int row = flat >> 3, cl = flat & 7, cg = cl ^ (row & 7);
      gl_lds16(phiT + (size_t)k0 * 4096 + row * 64 + cg * 8,
               &Psm[(v * 256 + wv * 64) * 8]);
    }
  }
  __syncthreads();  // U + P0 resident
  int wm = wv * 32;
  f16x8 af[2][2];
#pragma unroll
  for (int ks = 0; ks < 2; ++ks)
#pragma unroll
    for (int x = 0; x < 2; ++x) {
      int m = wm + x * 16 + (lane & 15);
      int ch = (ks * 4 + (lane >> 4)) ^ (m & 7);
      af[ks][x] = *(const f16x8*)&Ubuf[m * 64 + ch * 8];
    }
  for (int ki = 0; ki < 4; ++ki) {
    int k = kg * 4 + ki;
    f32x4 zero = {0.f, 0.f, 0.f, 0.f};
    f32x4 acc[2][4];
#pragma unroll
    for (int x = 0; x < 2; ++x)
#pragma unroll
      for (int y = 0; y < 4; ++y) acc[x][y] = zero;
#pragma unroll
    for (int ks = 0; ks < 2; ++ks) {
      f16x8 bf[4];
#pragma unroll
      for (int y = 0; y < 4; ++y) {
        int n = y * 16 + (lane & 15);
        int ch = (ks * 4 + (lane >> 4)) ^ (n & 7);
        bf[y] = *(const f16x8*)&Psm[n * 64 + ch * 8];
      }
#pragma unroll
      for (int x = 0; x < 2; ++x)
#pragma unroll
        for (int y = 0; y < 4; ++y)
          acc[x][y] = __builtin_amdgcn_mfma_f32_16x16x32_f16(af[ks][x], bf[y], acc[x][y], 0, 0, 0);
    }
    __syncthreads();  // Psm reads + (iter0) af Ubuf reads done everywhere
    // transpose C (128 sigma x 64 e) into Ubuf as Csm[e][sigma], stride 130
#pragma unroll
    for (int x = 0; x < 2; ++x)
#pragma unroll
      for (int y = 0; y < 4; ++y) {
        int e = y * 16 + (lane & 15);
        int sg = wm + x * 16 + ((lane >> 4) << 2);
        f16x4 pk;
        pk[0] = (f16)acc[x][y][0]; pk[1] = (f16)acc[x][y][1];
        pk[2] = (f16)acc[x][y][2]; pk[3] = (f16)acc[x][y][3];
        *(f16x4*)&Ubuf[e * 130 + sg] = pk;
      }
    if (ki < 3) {  // prefetch next P (Psm safe to overwrite after sync above)
      int kn = k + 1;
#pragma unroll
      for (int v = 0; v < 2; ++v) {
        int flat = v * 256 + tid;
        int row = flat >> 3, cl = flat & 7, cg = cl ^ (row & 7);
        gl_lds16(phiT + (size_t)kn * 4096 + row * 64 + cg * 8,
                 &Psm[(v * 256 + wv * 64) * 8]);
      }
    }
    __syncthreads();  // Csm visible; P(kn) drained (implicit vmcnt(0))
    // coalesced stores: 1024 chunks of 16B; 16 lanes cover 256B of one e-row
#pragma unroll
    for (int pass = 0; pass < 4; ++pass) {
      int g = pass * 256 + tid;
      int e = g >> 4, ch = g & 15;
      f16x8 val = *(const f16x8*)&Ubuf[e * 130 + ch * 8];
      *(f16x8*)&W2T[((size_t)((b * 24 + k) * 64 + e)) * 2048 + s0 + ch * 8] = val;
    }
  }
}

// ---- k_main: causal block-Toeplitz GEMM, 128x128 tiles, diag-major grid.
// R17: half-K-step software pipeline that PRESERVES 3 blocks/CU.
// R16 lesson (measured): full-tile dbuf (74 KB LDS) cut residency 3->2 and
// regressed 129->153us despite counted vmcnt. Fix: split the 128-wide s
// contraction into two 64-wide halves; double-buffer the 16 KB B-halves and
// the 5 KB D table => 42 KB LDS total, 3 blocks/CU retained. 48 half-steps:
// stage(g+1) issued before compute(g); raw s_barrier + counted vmcnt keeps
// the next half-tile in flight under the 32-MFMA cluster (setprio-wrapped).
__global__ __launch_bounds__(256, 3) void k_main(const f16* __restrict__ Dpre,
                                                 const f16* __restrict__ W2T,
                                                 float* __restrict__ out) {
  __shared__ __align__(16) f16 Bh[2][64 * 128];  // 2 x 16 KB: 128 rows x 64 s
  __shared__ __align__(16) f16 Dsm[2][2560];     // 2 x 5 KB
  int nt = blockIdx.x;
  int q = blockIdx.y;
  int diag = 0, off = 0;
  while (off + (16 - diag) <= q) { off += 16 - diag; ++diag; }
  int st = q - off;
  int mt = st + diag;
  int tid = threadIdx.x, lane = tid & 63, wv = tid >> 6;
  int wm = (wv & 1) * 64, wn = (wv >> 1) * 64;
  int b0 = nt * 2;
  int ml = lane & 15, qv = lane >> 4;
  int p264 = (7 - (ml & 7)) * 264;           // phase row in Dsm
  int yb = (ml < 8 ? 120 : 112) - wm;        // y0 = s0 - x*16 + yb

  f32x4 zero = {0.f, 0.f, 0.f, 0.f};
  f32x4 acc[4][4];
#pragma unroll
  for (int x = 0; x < 4; ++x)
#pragma unroll
    for (int y = 0; y < 4; ++y) acc[x][y] = zero;

  const f16* dplane = Dpre + (size_t)(diag * 24) * 2560;

  // D table stage: 320 chunks (256 all-waves + 64 by wave 0). 1 op/wave (+1 w0).
  auto stageD = [&](int buf, int kk) {
    const f16* dk = dplane + kk * 2560;
    gl_lds16(dk + tid * 8, &Dsm[buf][wv * 512]);
    if (wv == 0) gl_lds16(dk + (256 + lane) * 8, &Dsm[buf][2048]);
  };
  // B half-tile stage: 128 n-rows x 64 s (16 KB), XOR-swizzled 16B chunks
  // (8 chunks/row, cg = cl ^ (row&7)). 4 ops/wave.
  auto stageB = [&](int buf, int kk, int h) {
    const size_t sbase = (size_t)st * 128 + h * 64;
#pragma unroll
    for (int v = 0; v < 4; ++v) {
      int flat = v * 256 + tid;
      int row = flat >> 3, cl = flat & 7, cg = cl ^ (row & 7);
      int bb = b0 + (row >> 6), e = row & 63;
      gl_lds16(W2T + ((size_t)((bb * 24 + kk) * 64 + e)) * 2048 + sbase + cg * 8,
               &Bh[buf][(v * 256 + wv * 64) * 8]);
    }
  };
  // 32-MFMA half-cluster: ks = 2h + {0,1}; B chunk index within half is
  // (ksl*4+qv) ^ (n&7); 16 lanes -> 2-way bank aliasing (free).
  auto computeH = [&](int h, int dbuf) {
    __builtin_amdgcn_s_setprio(1);
#pragma unroll
    for (int ksl = 0; ksl < 2; ++ksl) {
      int ks = h * 2 + ksl;
      int s0q = ks * 32 + qv * 8;
      f16x8 af[4], bf[4];
#pragma unroll
      for (int x = 0; x < 4; ++x)
        af[x] = *(const f16x8*)&Dsm[dbuf][p264 + s0q - x * 16 + yb];
#pragma unroll
      for (int y = 0; y < 4; ++y) {
        int n = wn + y * 16 + ml;
        int cl = (ksl * 4 + qv) ^ (n & 7);
        bf[y] = *(const f16x8*)&Bh[h][n * 64 + cl * 8];
      }
#pragma unroll
      for (int x = 0; x < 4; ++x)
#pragma unroll
        for (int y = 0; y < 4; ++y)
          acc[x][y] = __builtin_amdgcn_mfma_f32_16x16x32_f16(af[x], bf[y], acc[x][y], 0, 0, 0);
    }
    __builtin_amdgcn_s_setprio(0);
  };

  // prologue: D(0) + B(0, h=0) in flight (5 ops/wave; 6 on wave 0)
  stageD(0, 0);
  stageB(0, 0, 0);

  for (int k = 0; k < 24; ++k) {
    const int dbuf = k & 1;
    // ---- half 0: compute Bh[0]; stage B(k, h=1) stays in flight (4 ops)
    stageB(1, k, 1);
    asm volatile("s_waitcnt vmcnt(4)" ::: "memory");  // drain D(k)+B(k,0)
    __builtin_amdgcn_s_barrier();
    __builtin_amdgcn_sched_barrier(0);
    computeH(0, dbuf);
    asm volatile("" ::: "memory");
    __builtin_amdgcn_sched_barrier(0);
    __builtin_amdgcn_s_barrier();  // Bh[0] reads done; may be overwritten next
    // ---- half 1: compute Bh[1]; stage D(k+1)+B(k+1, h=0) in flight (5/6 ops)
    if (k < 23) {
      stageD(dbuf ^ 1, k + 1);
      stageB(0, k + 1, 0);
      if (wv == 0)
        asm volatile("s_waitcnt vmcnt(6)" ::: "memory");  // drain B(k,1)
      else
        asm volatile("s_waitcnt vmcnt(5)" ::: "memory");
    } else {
      asm volatile("s_waitcnt vmcnt(0)" ::: "memory");
    }
    __builtin_amdgcn_s_barrier();
    __builtin_amdgcn_sched_barrier(0);
    computeH(1, dbuf);
    asm volatile("" ::: "memory");
    __builtin_amdgcn_sched_barrier(0);
    __builtin_amdgcn_s_barrier();  // Bh[1]/Dsm[dbuf] reads done
  }

  int t0 = mt * 128 + wm;
  int n0 = nt * 128 + wn;
#pragma unroll
  for (int x = 0; x < 4; ++x) {
    int rbase = t0 + x * 16 + (qv << 2);
#pragma unroll
    for (int y = 0; y < 4; ++y) {
      int col = n0 + y * 16 + ml;
      int b = col >> 6, e = col & 63;
#pragma unroll
      for (int r = 0; r < 4; ++r)
        atomicAdd(&out[((size_t)(b * 2048 + rbase + r)) * 64 + e], acc[x][y][r]);
    }
  }
}

extern "C" void kernel_launch(void* const* d_in, const int* in_sizes, int n_in,
                              void* d_out, int out_size, void* d_ws, size_t ws_size,
                              hipStream_t stream) {
  const float* inputs = (const float*)d_in[0];  // [16,2048,64]
  const float* m_phi = (const float*)d_in[1];   // [1536,64]
  const float* ev = (const float*)d_in[2];      // [24]
  const float* evec = (const float*)d_in[3];    // [2048,24]
  float* out = (float*)d_out;                   // [16,2048,64] fp32
  char* ws = (char*)d_ws;
  // ws layout: Dpre 1,966,080 | phiT 196,608 | uin 4,194,304 | W2T 100,663,296
  f16* Dpre = (f16*)(ws);
  f16* phiT = (f16*)(ws + 1966080);
  f16* uin = (f16*)(ws + 2162688);
  f16* W2T = (f16*)(ws + 6356992);

  hipLaunchKernelGGL(k_pre0, dim3(728), dim3(256), 0, stream,
                     inputs, m_phi, ev, evec, phiT, uin, Dpre, out);
  hipLaunchKernelGGL(k_w, dim3(1536), dim3(256), 0, stream, uin, phiT, W2T);
  hipLaunchKernelGGL(k_main, dim3(8, 136), dim3(256), 0, stream, Dpre, W2T, out);
}